// Round 8
// baseline (868.689 us; speedup 1.0000x reference)
//
#include <hip/hip_runtime.h>

#define BB 8
#define HH 512
#define WW 1024
#define PLANE ((size_t)HH * WW)
#define TILE 32
#define HALO 2
#define LW (TILE + 2*HALO)   // 36
// pass1 big tile + gather staging window
#define BT 64                // tile 64x64
#define GH 16                // gather halo
#define SW 96                // staging window 96x96
#define SP 100               // padded stride (16B-aligned rows, 4-bank rotation/row)

__device__ __forceinline__ float sigm(float v) { return 1.0f / (1.0f + __expf(-v)); }

// ---------- fallback helpers ----------
__device__ __forceinline__ float2 ld2c(const float* __restrict__ row, int x0) {
    if ((unsigned)x0 < (unsigned)(WW - 1)) {
        return *reinterpret_cast<const float2*>(row + x0);
    }
    float v = row[x0 < 0 ? 0 : WW - 1];
    return make_float2(v, v);
}

template<int C>
__device__ __forceinline__ void bilinN(const float* __restrict__ base,
                                       float gx, float gy, float out[C]) {
    float x0f = floorf(gx), y0f = floorf(gy);
    float ax = gx - x0f, ay = gy - y0f;
    int x0 = (int)x0f, y0 = (int)y0f;
    int y0i = min(max(y0, 0), HH - 1);
    int y1i = min(max(y0 + 1, 0), HH - 1);
    float w00 = (1.f - ay) * (1.f - ax), w01 = (1.f - ay) * ax;
    float w10 = ay * (1.f - ax), w11 = ay * ax;
#pragma unroll
    for (int c = 0; c < C; ++c) {
        const float* pl = base + c * PLANE;
        float2 r0 = ld2c(pl + (size_t)y0i * WW, x0);
        float2 r1 = ld2c(pl + (size_t)y1i * WW, x0);
        out[c] = w00 * r0.x + w01 * r0.y + w10 * r1.x + w11 * r1.y;
    }
}

__device__ __forceinline__ void block_reduce_2(float a, float b, float* red,
                                               float* acc, int addB) {
    int tid = threadIdx.x;
#pragma unroll
    for (int off = 32; off > 0; off >>= 1) {
        a += __shfl_down(a, off);
        b += __shfl_down(b, off);
    }
    int wid = tid >> 6;
    if ((tid & 63) == 0) { red[wid] = a; red[4 + wid] = b; }
    __syncthreads();
    if (tid == 0) {
        atomicAdd(&acc[0], red[0] + red[1] + red[2] + red[3]);
        if (addB) atomicAdd(&acc[1], red[4] + red[5] + red[6] + red[7]);
    }
}

// ---------- stage one plane's 96x96 window (9 float4 per thread) ----------
__device__ __forceinline__ void stage_plane(const float* __restrict__ pl,
                                            float (* __restrict__ st)[SP],
                                            int tx0, int ty0, bool interior) {
    const int tid = threadIdx.x;
    if (interior) {
#pragma unroll
        for (int k = 0; k < 9; ++k) {
            int s = tid + k * 256;                 // 0..2303
            int sy = s / 24;                       // 24 float4 per 96-col row
            int sx4 = (s - sy * 24) * 4;
            float4 v = *(const float4*)(pl + (size_t)(ty0 - GH + sy) * WW + (tx0 - GH + sx4));
            *(float4*)&st[sy][sx4] = v;
        }
    } else {
#pragma unroll
        for (int k = 0; k < 9; ++k) {
            int s = tid + k * 256;
            int sy = s / 24;
            int sx4 = (s - sy * 24) * 4;
            int gy = min(max(ty0 - GH + sy, 0), HH - 1);
            const float* row = pl + (size_t)gy * WW;
#pragma unroll
            for (int e = 0; e < 4; ++e) {
                int gx = min(max(tx0 - GH + sx4 + e, 0), WW - 1);
                st[sy][sx4 + e] = row[gx];
            }
        }
    }
}

// bilinear gather from staged window; rare out-of-window lanes -> clamped global
__device__ __forceinline__ float gather1(const float (* __restrict__ st)[SP],
                                         const float* __restrict__ pl,
                                         float X, float Y, int tx0, int ty0) {
    float x0f = floorf(X), y0f = floorf(Y);
    float ax = X - x0f, ay = Y - y0f;
    int x0 = (int)x0f, y0 = (int)y0f;
    int sx = x0 - (tx0 - GH);
    int sy = y0 - (ty0 - GH);
    float v00, v01, v10, v11;
    if ((unsigned)sx < (unsigned)(SW - 1) && (unsigned)sy < (unsigned)(SW - 1)) {
        v00 = st[sy][sx];     v01 = st[sy][sx + 1];
        v10 = st[sy + 1][sx]; v11 = st[sy + 1][sx + 1];
    } else {
        int x0i = min(max(x0, 0), WW - 1), x1i = min(max(x0 + 1, 0), WW - 1);
        int y0i = min(max(y0, 0), HH - 1), y1i = min(max(y0 + 1, 0), HH - 1);
        v00 = pl[(size_t)y0i * WW + x0i]; v01 = pl[(size_t)y0i * WW + x1i];
        v10 = pl[(size_t)y1i * WW + x0i]; v11 = pl[(size_t)y1i * WW + x1i];
    }
    return (1.f - ay) * ((1.f - ax) * v00 + ax * v01)
         + ay * ((1.f - ax) * v10 + ax * v11);
}

// ---- Pass 1: 64x64 tile, 16 px/thread, 96x96 staged window reused over 5 planes ----
__global__ __launch_bounds__(256)
void pass1_kernel(const float* __restrict__ flowa, const float* __restrict__ flowb,
                  const float* __restrict__ imga, const float* __restrict__ imgb,
                  const float* __restrict__ target,
                  float* __restrict__ e0p, float* __restrict__ e1p,
                  float* __restrict__ e2p, float* __restrict__ mp,
                  float* __restrict__ acc, int isFwd) {
    __shared__ float st[SW][SP];   // 38.4 KB
    __shared__ float red[8];

    const int tid = threadIdx.x;
    const int bx = blockIdx.x, by = blockIdx.y, b = blockIdx.z;
    const int tx0 = bx * BT, ty0 = by * BT;
    const bool interior = (bx >= 1 && bx <= (WW / BT - 2) && by >= 1 && by <= (HH / BT - 2));
    const size_t fbase = (size_t)(b * 2) * PLANE;
    const size_t ibase = (size_t)(b * 3) * PLANE;
    const size_t obase = (size_t)b * PLANE;

    const float* fbx = flowb + fbase;
    const float* fby = flowb + fbase + PLANE;

    float fx16[16], fy16[16], mask16[16], A16[16], wfx16[16];
    float local = 0.f, lepe = 0.f;

    // ---- phase 0: stage flowb-x; per-px own/neighbor/target loads ----
    stage_plane(fbx, st, tx0, ty0, interior);
#pragma unroll
    for (int i = 0; i < 16; ++i) {
        int p = i * 256 + tid;
        int lx = p & 63, ly = p >> 6;
        int x = tx0 + lx, y = ty0 + ly;
        size_t fi = fbase + (size_t)y * WW + x;
        float fx = flowa[fi], fy = flowa[fi + PLANE];
        fx16[i] = fx; fy16[i] = fy;
        int xr = min(x + 1, WW - 1), yd = min(y + 1, HH - 1);
        size_t fir = fbase + (size_t)y * WW + xr;
        size_t fid = fbase + (size_t)yd * WW + x;
        float dxr = flowa[fir] - fx, dyr = flowa[fir + PLANE] - fy;
        float dxd = flowa[fid] - fx, dyd = flowa[fid + PLANE] - fy;
        float sm = ((x < WW - 1) ? (dxr * dxr + dyr * dyr) : 0.f)
                 + ((y < HH - 1) ? (dxd * dxd + dyd * dyd) : 0.f);
        local += sqrtf(sm + 1e-5f);
        if (isFwd) {
            float dx1 = fx - target[fi], dy1 = fy - target[fi + PLANE];
            lepe += sqrtf(dx1 * dx1 + dy1 * dy1);
        }
        float X = (float)x + fx, Y = (float)y + fy;
        mask16[i] = sigm(X + 0.5f) * (1.f - sigm(X - ((float)WW - 0.5f)))
                  * sigm(Y + 0.5f) * (1.f - sigm(Y - ((float)HH - 0.5f)));
    }
    __syncthreads();
#pragma unroll
    for (int i = 0; i < 16; ++i) {
        int p = i * 256 + tid;
        int x = tx0 + (p & 63), y = ty0 + (p >> 6);
        wfx16[i] = gather1(st, fbx, (float)x + fx16[i], (float)y + fy16[i], tx0, ty0);
    }
    __syncthreads();

    // ---- phase 1: stage flowb-y; gather wfy; finish occ mask + fb/maskcost ----
    stage_plane(fby, st, tx0, ty0, interior);
    __syncthreads();
#pragma unroll
    for (int i = 0; i < 16; ++i) {
        int p = i * 256 + tid;
        int x = tx0 + (p & 63), y = ty0 + (p >> 6);
        float fx = fx16[i], fy = fy16[i];
        float wfy = gather1(st, fby, (float)x + fx, (float)y + fy, tx0, ty0);
        float wfx = wfx16[i];
        float mag = fx * fx + fy * fy + wfx * wfx + wfy * wfy;
        float sx = fx + wfx, sy = fy + wfy;
        float d2 = sx * sx + sy * sy;
        float mask = mask16[i] * (1.f - sigm(d2 - (0.01f * mag + 0.5f)));
        mask16[i] = mask;
        local += 12.4f * (1.f - mask) + sqrtf(d2 + 1e-5f) * mask;
    }
    __syncthreads();

    // ---- phases 2..4: per channel: stage imgb_c; gather; e = imga_c - w; store e ----
#pragma unroll
    for (int c = 0; c < 3; ++c) {
        const float* pl = imgb + ibase + c * PLANE;
        const float* apl = imga + ibase + c * PLANE;
        float* ep = (c == 0) ? e0p : (c == 1) ? e1p : e2p;
        stage_plane(pl, st, tx0, ty0, interior);
        __syncthreads();
#pragma unroll
        for (int i = 0; i < 16; ++i) {
            int p = i * 256 + tid;
            int x = tx0 + (p & 63), y = ty0 + (p >> 6);
            size_t pi = (size_t)y * WW + x;
            float a = apl[pi];
            float w = gather1(st, pl, (float)x + fx16[i], (float)y + fy16[i], tx0, ty0);
            float e = a - w;
            if (c == 0) A16[i] = e * e; else A16[i] += e * e;
            ep[obase + pi] = e;
        }
        if (c < 2) __syncthreads();
    }

    // ---- epilogue: data term + mask store ----
#pragma unroll
    for (int i = 0; i < 16; ++i) {
        int p = i * 256 + tid;
        int x = tx0 + (p & 63), y = ty0 + (p >> 6);
        local += sqrtf(A16[i] + 1e-5f) * mask16[i];
        mp[obase + (size_t)y * WW + x] = mask16[i];
    }

    block_reduce_2(local, lepe, red, acc, isFwd);
}

// ---- Pass 2: 5-point-cross stencil on planar e (zero-padded), adds GAMMA*sqrt(C)*mask ----
__global__ __launch_bounds__(256)
void pass2_kernel(const float* __restrict__ e0p, const float* __restrict__ e1p,
                  const float* __restrict__ e2p, const float* __restrict__ mp,
                  float* __restrict__ acc) {
    __shared__ float te[3][LW][LW + 4];   // 17.3 KB
    __shared__ float red[8];
    const int tx0 = blockIdx.x * TILE, ty0 = blockIdx.y * TILE;
    const int b = blockIdx.z;
    const size_t obase = (size_t)b * PLANE;

#pragma unroll
    for (int c = 0; c < 3; ++c) {
        const float* ep = (c == 0) ? e0p : (c == 1) ? e1p : e2p;
        for (int p = threadIdx.x; p < LW * LW; p += 256) {
            int hy = p / LW, hx = p - hy * LW;
            int gy = ty0 + hy - HALO, gx = tx0 + hx - HALO;
            float v = 0.f;
            if ((unsigned)gx < (unsigned)WW && (unsigned)gy < (unsigned)HH)
                v = ep[obase + (size_t)gy * WW + gx];
            te[c][hy][hx] = v;
        }
    }
    __syncthreads();

    float local = 0.f;
    const float T0 = 1.f / 12.f, T1 = 2.f / 3.f;
#pragma unroll
    for (int i = 0; i < 4; ++i) {
        int p = i * 256 + threadIdx.x;
        int ly = p >> 5, lx = p & 31;
        float C = 0.f;
#pragma unroll
        for (int c = 0; c < 3; ++c) {
            float gh = T1 * (te[c][ly + 2][lx + 1] - te[c][ly + 2][lx + 3])
                     + T0 * (te[c][ly + 2][lx + 4] - te[c][ly + 2][lx]);
            float gv = T1 * (te[c][ly + 1][lx + 2] - te[c][ly + 3][lx + 2])
                     + T0 * (te[c][ly + 4][lx + 2] - te[c][ly][lx + 2]);
            C += gh * gh + gv * gv;
        }
        float m = mp[obase + (size_t)(ty0 + ly) * WW + (tx0 + lx)];
        local += sqrtf(C + 1e-5f) * m;
    }
    block_reduce_2(local, 0.f, red, acc, 0);
}

// ---- Fallback (R1 structure) if ws is too small ----
template<bool EPE>
__global__ __launch_bounds__(256)
void dir_kernel_fb(const float* __restrict__ flowa, const float* __restrict__ flowb,
                   const float* __restrict__ imga, const float* __restrict__ imgb,
                   const float* __restrict__ target, float* __restrict__ acc) {
    __shared__ float lds_w[3][LW][LW];
    __shared__ float lds_a[3][LW][LW];
    __shared__ float red[8];
    const int b = blockIdx.z;
    const int tx0 = blockIdx.x * TILE, ty0 = blockIdx.y * TILE;
    const int tid = threadIdx.x;
    const size_t fbase = (size_t)(b * 2) * PLANE;
    const size_t ibase = (size_t)(b * 3) * PLANE;

    for (int p = tid; p < LW * LW; p += 256) {
        int hy = p / LW, hx = p - hy * LW;
        int gy = ty0 + hy - HALO, gx = tx0 + hx - HALO;
        float w[3] = {0.f, 0.f, 0.f};
        float a0 = 0.f, a1 = 0.f, a2 = 0.f;
        if ((unsigned)gx < (unsigned)WW && (unsigned)gy < (unsigned)HH) {
            size_t fi = fbase + (size_t)gy * WW + gx;
            bilinN<3>(imgb + ibase, (float)gx + flowa[fi], (float)gy + flowa[fi + PLANE], w);
            size_t ii = ibase + (size_t)gy * WW + gx;
            a0 = imga[ii]; a1 = imga[ii + PLANE]; a2 = imga[ii + 2 * PLANE];
        }
        lds_w[0][hy][hx] = w[0]; lds_w[1][hy][hx] = w[1]; lds_w[2][hy][hx] = w[2];
        lds_a[0][hy][hx] = a0;   lds_a[1][hy][hx] = a1;   lds_a[2][hy][hx] = a2;
    }
    __syncthreads();

    float local = 0.f, lepe = 0.f;
    const float T0 = 1.f / 12.f, T1 = 2.f / 3.f;
#pragma unroll
    for (int i = 0; i < 4; ++i) {
        int p = i * 256 + tid;
        int ly = p >> 5, lx = p & 31;
        int y = ty0 + ly, x = tx0 + lx;
        size_t fi = fbase + (size_t)y * WW + x;
        float fx = flowa[fi], fy = flowa[fi + PLANE];
        float X = (float)x + fx, Y = (float)y + fy;
        float mask = sigm(X + 0.5f) * (1.f - sigm(X - ((float)WW - 0.5f)))
                   * sigm(Y + 0.5f) * (1.f - sigm(Y - ((float)HH - 0.5f)));
        float wf[2];
        bilinN<2>(flowb + fbase, X, Y, wf);
        float mag = fx * fx + fy * fy + wf[0] * wf[0] + wf[1] * wf[1];
        float sx = fx + wf[0], sy = fy + wf[1];
        float d2 = sx * sx + sy * sy;
        mask *= 1.f - sigm(d2 - (0.01f * mag + 0.5f));
        float A = 0.f;
#pragma unroll
        for (int c = 0; c < 3; ++c) {
            float d = lds_a[c][ly + 2][lx + 2] - lds_w[c][ly + 2][lx + 2];
            A += d * d;
        }
        float sm = 0.f;
        if (x < WW - 1) {
            float dfx = flowa[fi + 1] - fx, dfy = flowa[fi + PLANE + 1] - fy;
            sm += dfx * dfx + dfy * dfy;
        }
        if (y < HH - 1) {
            float dfx = flowa[fi + WW] - fx, dfy = flowa[fi + PLANE + WW] - fy;
            sm += dfx * dfx + dfy * dfy;
        }
        float C = 0.f;
#pragma unroll
        for (int c = 0; c < 3; ++c) {
            float gha = T1 * (lds_a[c][ly + 2][lx + 1] - lds_a[c][ly + 2][lx + 3])
                      + T0 * (lds_a[c][ly + 2][lx + 4] - lds_a[c][ly + 2][lx]);
            float ghw = T1 * (lds_w[c][ly + 2][lx + 1] - lds_w[c][ly + 2][lx + 3])
                      + T0 * (lds_w[c][ly + 2][lx + 4] - lds_w[c][ly + 2][lx]);
            float d = gha - ghw; C += d * d;
            float gva = T1 * (lds_a[c][ly + 1][lx + 2] - lds_a[c][ly + 3][lx + 2])
                      + T0 * (lds_a[c][ly + 4][lx + 2] - lds_a[c][ly][lx + 2]);
            float gvw = T1 * (lds_w[c][ly + 1][lx + 2] - lds_w[c][ly + 3][lx + 2])
                      + T0 * (lds_w[c][ly + 4][lx + 2] - lds_w[c][ly][lx + 2]);
            d = gva - gvw; C += d * d;
        }
        local += sqrtf(A + 1e-5f) * mask + sqrtf(sm + 1e-5f)
               + sqrtf(C + 1e-5f) * mask + 12.4f * (1.f - mask)
               + sqrtf(d2 + 1e-5f) * mask;
        if (EPE) {
            float dx1 = fx - target[fi], dy1 = fy - target[fi + PLANE];
            lepe += sqrtf(dx1 * dx1 + dy1 * dy1);
        }
    }
    block_reduce_2(local, lepe, red, acc, EPE ? 1 : 0);
}

__global__ void finalize_kernel(const float* __restrict__ acc, float* __restrict__ out) {
    out[0] = acc[0] / (float)BB;
    out[1] = acc[1] / (float)((size_t)BB * HH * WW);
}

extern "C" void kernel_launch(void* const* d_in, const int* in_sizes, int n_in,
                              void* d_out, int out_size, void* d_ws, size_t ws_size,
                              hipStream_t stream) {
    const float* flowf  = (const float*)d_in[0];
    const float* flowb  = (const float*)d_in[1];
    const float* img1   = (const float*)d_in[2];
    const float* img2   = (const float*)d_in[3];
    const float* target = (const float*)d_in[4];
    float* out = (float*)d_out;
    float* acc = (float*)d_ws;

    hipMemsetAsync(acc, 0, 16, stream);

    const size_t pbytes = (size_t)BB * PLANE * sizeof(float);
    const size_t need = 16 + 4 * pbytes;   // ~64 MB (e0,e1,e2,m planes)
    if (ws_size >= need) {
        float* e0p = (float*)((char*)d_ws + 16);
        float* e1p = e0p + BB * PLANE;
        float* e2p = e1p + BB * PLANE;
        float* mp  = e2p + BB * PLANE;
        dim3 g1(WW / BT, HH / BT, BB);
        dim3 g2(WW / TILE, HH / TILE, BB);
        // forward
        pass1_kernel<<<g1, 256, 0, stream>>>(flowf, flowb, img1, img2, target,
                                             e0p, e1p, e2p, mp, acc, 1);
        pass2_kernel<<<g2, 256, 0, stream>>>(e0p, e1p, e2p, mp, acc);
        // backward (reuses planes)
        pass1_kernel<<<g1, 256, 0, stream>>>(flowb, flowf, img2, img1, nullptr,
                                             e0p, e1p, e2p, mp, acc, 0);
        pass2_kernel<<<g2, 256, 0, stream>>>(e0p, e1p, e2p, mp, acc);
    } else {
        dim3 grid(WW / TILE, HH / TILE, BB);
        dir_kernel_fb<true ><<<grid, 256, 0, stream>>>(flowf, flowb, img1, img2, target, acc);
        dir_kernel_fb<false><<<grid, 256, 0, stream>>>(flowb, flowf, img2, img1, nullptr, acc);
    }

    finalize_kernel<<<1, 1, 0, stream>>>(acc, out);
}

// Round 9
// 529.715 us; speedup vs baseline: 1.6399x; 1.6399x over previous
//
#include <hip/hip_runtime.h>

#define BB 8
#define HH 512
#define WW 1024
#define PLANE ((size_t)HH * WW)
#define TILE 32
#define HALO 2
#define LW (TILE + 2*HALO)   // 36
#define GH 16
#define SW 64
#define SP 68                // padded stride

__device__ __forceinline__ float sigm(float v) { return 1.0f / (1.0f + __expf(-v)); }

// ---------- fallback helpers ----------
__device__ __forceinline__ float2 ld2c(const float* __restrict__ row, int x0) {
    if ((unsigned)x0 < (unsigned)(WW - 1)) {
        return *reinterpret_cast<const float2*>(row + x0);
    }
    float v = row[x0 < 0 ? 0 : WW - 1];
    return make_float2(v, v);
}

template<int C>
__device__ __forceinline__ void bilinN(const float* __restrict__ base,
                                       float gx, float gy, float out[C]) {
    float x0f = floorf(gx), y0f = floorf(gy);
    float ax = gx - x0f, ay = gy - y0f;
    int x0 = (int)x0f, y0 = (int)y0f;
    int y0i = min(max(y0, 0), HH - 1);
    int y1i = min(max(y0 + 1, 0), HH - 1);
    float w00 = (1.f - ay) * (1.f - ax), w01 = (1.f - ay) * ax;
    float w10 = ay * (1.f - ax), w11 = ay * ax;
#pragma unroll
    for (int c = 0; c < C; ++c) {
        const float* pl = base + c * PLANE;
        float2 r0 = ld2c(pl + (size_t)y0i * WW, x0);
        float2 r1 = ld2c(pl + (size_t)y1i * WW, x0);
        out[c] = w00 * r0.x + w01 * r0.y + w10 * r1.x + w11 * r1.y;
    }
}

__device__ __forceinline__ void block_reduce_2(float a, float b, float* red,
                                               float* acc, int addB) {
    int tid = threadIdx.x;
#pragma unroll
    for (int off = 32; off > 0; off >>= 1) {
        a += __shfl_down(a, off);
        b += __shfl_down(b, off);
    }
    int wid = tid >> 6;
    if ((tid & 63) == 0) { red[wid] = a; red[4 + wid] = b; }
    __syncthreads();
    if (tid == 0) {
        atomicAdd(&acc[0], red[0] + red[1] + red[2] + red[3]);
        if (addB) atomicAdd(&acc[1], red[4] + red[5] + red[6] + red[7]);
    }
}

// ---------- async staging: global -> regs (issue early), regs -> LDS (write late) ----------
__device__ __forceinline__ void stage_load(const float* __restrict__ pl,
                                           int tx0, int ty0, bool interior,
                                           int tid, float4 r[4]) {
    const int sy = tid >> 2;            // 0..63
    const int sx0 = (tid & 3) << 4;     // 0,16,32,48
    if (interior) {
        const float* src = pl + (size_t)(ty0 - GH + sy) * WW + (tx0 - GH + sx0);
#pragma unroll
        for (int k = 0; k < 4; ++k) r[k] = ((const float4*)src)[k];
    } else {
        int gy = min(max(ty0 - GH + sy, 0), HH - 1);
        const float* row = pl + (size_t)gy * WW;
#pragma unroll
        for (int k = 0; k < 4; ++k) {
            float t0 = row[min(max(tx0 - GH + sx0 + k * 4 + 0, 0), WW - 1)];
            float t1 = row[min(max(tx0 - GH + sx0 + k * 4 + 1, 0), WW - 1)];
            float t2 = row[min(max(tx0 - GH + sx0 + k * 4 + 2, 0), WW - 1)];
            float t3 = row[min(max(tx0 - GH + sx0 + k * 4 + 3, 0), WW - 1)];
            r[k] = make_float4(t0, t1, t2, t3);
        }
    }
}

__device__ __forceinline__ void stage_write(float (* __restrict__ st)[SP],
                                            int tid, const float4 r[4]) {
    const int sy = tid >> 2;
    const int sx0 = (tid & 3) << 4;
    float4* dst = (float4*)&st[sy][sx0];
#pragma unroll
    for (int k = 0; k < 4; ++k) dst[k] = r[k];
}

// bilinear gather from staged window; rare out-of-window lanes -> clamped global
__device__ __forceinline__ float gather1(const float (* __restrict__ st)[SP],
                                         const float* __restrict__ pl,
                                         float X, float Y, int tx0, int ty0) {
    float x0f = floorf(X), y0f = floorf(Y);
    float ax = X - x0f, ay = Y - y0f;
    int x0 = (int)x0f, y0 = (int)y0f;
    int sx = x0 - (tx0 - GH);
    int sy = y0 - (ty0 - GH);
    float v00, v01, v10, v11;
    if ((unsigned)sx < (unsigned)(SW - 1) && (unsigned)sy < (unsigned)(SW - 1)) {
        v00 = st[sy][sx];     v01 = st[sy][sx + 1];
        v10 = st[sy + 1][sx]; v11 = st[sy + 1][sx + 1];
    } else {
        int x0i = min(max(x0, 0), WW - 1), x1i = min(max(x0 + 1, 0), WW - 1);
        int y0i = min(max(y0, 0), HH - 1), y1i = min(max(y0 + 1, 0), HH - 1);
        v00 = pl[(size_t)y0i * WW + x0i]; v01 = pl[(size_t)y0i * WW + x1i];
        v10 = pl[(size_t)y1i * WW + x0i]; v11 = pl[(size_t)y1i * WW + x1i];
    }
    return (1.f - ay) * ((1.f - ax) * v00 + ax * v01)
         + ay * ((1.f - ax) * v10 + ax * v11);
}

// ---- Pass 1: 32x32 tile, async double-buffered staging pipeline over 5 planes ----
__global__ __launch_bounds__(256)
void pass1_kernel(const float* __restrict__ flowa, const float* __restrict__ flowb,
                  const float* __restrict__ imga, const float* __restrict__ imgb,
                  const float* __restrict__ target, float4* __restrict__ ebuf,
                  float* __restrict__ acc, int isFwd) {
    __shared__ float st[2][SW][SP];   // 34.8 KB
    __shared__ float red[8];

    const int tid = threadIdx.x;
    const int bx = blockIdx.x, by = blockIdx.y, b = blockIdx.z;
    const int tx0 = bx * TILE, ty0 = by * TILE;
    // interior: the 64x64 window [t-16, t+47] fully inside the image
    const bool interior = (tx0 >= GH) && (tx0 + TILE + GH + 15 < WW) &&
                          (ty0 >= GH) && (ty0 + TILE + GH + 15 < HH);
    const size_t fbase = (size_t)(b * 2) * PLANE;
    const size_t ibase = (size_t)(b * 3) * PLANE;

    const float* fbx = flowb + fbase;
    const float* fby = flowb + fbase + PLANE;
    const float* ib0 = imgb + ibase;
    const float* ib1 = ib0 + PLANE;
    const float* ib2 = ib1 + PLANE;

    float4 rA[4], rB[4];
    // P0-issue: both flow planes' windows -> regs (8 float4 in flight)
    stage_load(fbx, tx0, ty0, interior, tid, rA);
    stage_load(fby, tx0, ty0, interior, tid, rB);

    float fx4[4], fy4[4], mask4[4], wfx4[4];
    float e04[4], e14[4], e24[4];
    float local = 0.f, lepe = 0.f;

    // P0-compute: per-px coalesced loads + flow-only terms (hides staging latency)
#pragma unroll
    for (int i = 0; i < 4; ++i) {
        int p = i * 256 + tid;
        int lx = p & 31, ly = p >> 5;
        int x = tx0 + lx, y = ty0 + ly;
        size_t fi = fbase + (size_t)y * WW + x;
        float fx = flowa[fi], fy = flowa[fi + PLANE];
        fx4[i] = fx; fy4[i] = fy;
        int xr = min(x + 1, WW - 1), yd = min(y + 1, HH - 1);
        size_t fir = fbase + (size_t)y * WW + xr;
        size_t fid = fbase + (size_t)yd * WW + x;
        float dxr = flowa[fir] - fx, dyr = flowa[fir + PLANE] - fy;
        float dxd = flowa[fid] - fx, dyd = flowa[fid + PLANE] - fy;
        float sm = ((x < WW - 1) ? (dxr * dxr + dyr * dyr) : 0.f)
                 + ((y < HH - 1) ? (dxd * dxd + dyd * dyd) : 0.f);
        local += sqrtf(sm + 1e-5f);
        if (isFwd) {
            float dx1 = fx - target[fi], dy1 = fy - target[fi + PLANE];
            lepe += sqrtf(dx1 * dx1 + dy1 * dy1);
        }
        float X = (float)x + fx, Y = (float)y + fy;
        mask4[i] = sigm(X + 0.5f) * (1.f - sigm(X - ((float)WW - 0.5f)))
                 * sigm(Y + 0.5f) * (1.f - sigm(Y - ((float)HH - 0.5f)));
    }

    // commit flow windows; issue img0 window
    stage_write(st[0], tid, rA);
    stage_load(ib0, tx0, ty0, interior, tid, rA);
    stage_write(st[1], tid, rB);
    __syncthreads();                               // b1

    // P1: gather wfx/wfy, finish occ/mask + fb/maskcost
#pragma unroll
    for (int i = 0; i < 4; ++i) {
        int p = i * 256 + tid;
        int x = tx0 + (p & 31), y = ty0 + (p >> 5);
        float fx = fx4[i], fy = fy4[i];
        float X = (float)x + fx, Y = (float)y + fy;
        float wfx = gather1(st[0], fbx, X, Y, tx0, ty0);
        float wfy = gather1(st[1], fby, X, Y, tx0, ty0);
        wfx4[i] = wfx;
        float mag = fx * fx + fy * fy + wfx * wfx + wfy * wfy;
        float sx = fx + wfx, sy = fy + wfy;
        float d2 = sx * sx + sy * sy;
        float mask = mask4[i] * (1.f - sigm(d2 - (0.01f * mag + 0.5f)));
        mask4[i] = mask;
        local += 12.4f * (1.f - mask) + sqrtf(d2 + 1e-5f) * mask;
    }
    __syncthreads();                               // b2 (st[0] readers done)

    stage_write(st[0], tid, rA);                   // img0
    stage_load(ib1, tx0, ty0, interior, tid, rB);  // issue img1
    __syncthreads();                               // b3

    // P3: gather img0 -> e0
#pragma unroll
    for (int i = 0; i < 4; ++i) {
        int p = i * 256 + tid;
        int x = tx0 + (p & 31), y = ty0 + (p >> 5);
        float a = imga[ibase + (size_t)y * WW + x];
        e04[i] = a - gather1(st[0], ib0, (float)x + fx4[i], (float)y + fy4[i], tx0, ty0);
    }
    __syncthreads();                               // b4

    stage_write(st[1], tid, rB);                   // img1
    stage_load(ib2, tx0, ty0, interior, tid, rA);  // issue img2
    __syncthreads();                               // b5

    // P5: gather img1 -> e1
#pragma unroll
    for (int i = 0; i < 4; ++i) {
        int p = i * 256 + tid;
        int x = tx0 + (p & 31), y = ty0 + (p >> 5);
        float a = imga[ibase + PLANE + (size_t)y * WW + x];
        e14[i] = a - gather1(st[1], ib1, (float)x + fx4[i], (float)y + fy4[i], tx0, ty0);
    }
    __syncthreads();                               // b6

    stage_write(st[0], tid, rA);                   // img2
    __syncthreads();                               // b7

    // P7: gather img2 -> e2; epilogue
#pragma unroll
    for (int i = 0; i < 4; ++i) {
        int p = i * 256 + tid;
        int x = tx0 + (p & 31), y = ty0 + (p >> 5);
        float a = imga[ibase + 2 * PLANE + (size_t)y * WW + x];
        e24[i] = a - gather1(st[0], ib2, (float)x + fx4[i], (float)y + fy4[i], tx0, ty0);
        float A = e04[i] * e04[i] + e14[i] * e14[i] + e24[i] * e24[i];
        local += sqrtf(A + 1e-5f) * mask4[i];
        ebuf[(size_t)b * PLANE + (size_t)y * WW + x] =
            make_float4(e04[i], e14[i], e24[i], mask4[i]);
    }

    block_reduce_2(local, lepe, red, acc, isFwd);
}

// ---- Pass 2: 5-point-cross stencil on e (zero-padded), adds GAMMA*sqrt(C)*mask ----
__global__ __launch_bounds__(256, 4)
void pass2_kernel(const float4* __restrict__ ebuf, float* __restrict__ acc) {
    __shared__ float4 t[LW][LW];   // 20.7 KB
    __shared__ float red[8];
    const int tx0 = blockIdx.x * TILE, ty0 = blockIdx.y * TILE;
    const int b = blockIdx.z;
    const float4* pb = ebuf + (size_t)b * PLANE;

    for (int p = threadIdx.x; p < LW * LW; p += 256) {
        int hy = p / LW, hx = p - hy * LW;
        int gy = ty0 + hy - HALO, gx = tx0 + hx - HALO;
        float4 v = make_float4(0.f, 0.f, 0.f, 0.f);
        if ((unsigned)gx < (unsigned)WW && (unsigned)gy < (unsigned)HH)
            v = pb[(size_t)gy * WW + gx];
        t[hy][hx] = v;
    }
    __syncthreads();

    float local = 0.f;
    const float T0 = 1.f / 12.f, T1 = 2.f / 3.f;
#pragma unroll
    for (int i = 0; i < 4; ++i) {
        int p = i * 256 + threadIdx.x;
        int ly = p >> 5, lx = p & 31;
        float4 hL1 = t[ly + 2][lx + 1], hR1 = t[ly + 2][lx + 3];
        float4 hL2 = t[ly + 2][lx],     hR2 = t[ly + 2][lx + 4];
        float4 vU1 = t[ly + 1][lx + 2], vD1 = t[ly + 3][lx + 2];
        float4 vU2 = t[ly][lx + 2],     vD2 = t[ly + 4][lx + 2];
        float C = 0.f, gh, gv;
        gh = T1 * (hL1.x - hR1.x) + T0 * (hR2.x - hL2.x);
        gv = T1 * (vU1.x - vD1.x) + T0 * (vD2.x - vU2.x);
        C += gh * gh + gv * gv;
        gh = T1 * (hL1.y - hR1.y) + T0 * (hR2.y - hL2.y);
        gv = T1 * (vU1.y - vD1.y) + T0 * (vD2.y - vU2.y);
        C += gh * gh + gv * gv;
        gh = T1 * (hL1.z - hR1.z) + T0 * (hR2.z - hL2.z);
        gv = T1 * (vU1.z - vD1.z) + T0 * (vD2.z - vU2.z);
        C += gh * gh + gv * gv;
        local += sqrtf(C + 1e-5f) * t[ly + 2][lx + 2].w;
    }
    block_reduce_2(local, 0.f, red, acc, 0);
}

// ---- Fallback (R1 structure) if ws is too small ----
template<bool EPE>
__global__ __launch_bounds__(256)
void dir_kernel_fb(const float* __restrict__ flowa, const float* __restrict__ flowb,
                   const float* __restrict__ imga, const float* __restrict__ imgb,
                   const float* __restrict__ target, float* __restrict__ acc) {
    __shared__ float lds_w[3][LW][LW];
    __shared__ float lds_a[3][LW][LW];
    __shared__ float red[8];
    const int b = blockIdx.z;
    const int tx0 = blockIdx.x * TILE, ty0 = blockIdx.y * TILE;
    const int tid = threadIdx.x;
    const size_t fbase = (size_t)(b * 2) * PLANE;
    const size_t ibase = (size_t)(b * 3) * PLANE;

    for (int p = tid; p < LW * LW; p += 256) {
        int hy = p / LW, hx = p - hy * LW;
        int gy = ty0 + hy - HALO, gx = tx0 + hx - HALO;
        float w[3] = {0.f, 0.f, 0.f};
        float a0 = 0.f, a1 = 0.f, a2 = 0.f;
        if ((unsigned)gx < (unsigned)WW && (unsigned)gy < (unsigned)HH) {
            size_t fi = fbase + (size_t)gy * WW + gx;
            bilinN<3>(imgb + ibase, (float)gx + flowa[fi], (float)gy + flowa[fi + PLANE], w);
            size_t ii = ibase + (size_t)gy * WW + gx;
            a0 = imga[ii]; a1 = imga[ii + PLANE]; a2 = imga[ii + 2 * PLANE];
        }
        lds_w[0][hy][hx] = w[0]; lds_w[1][hy][hx] = w[1]; lds_w[2][hy][hx] = w[2];
        lds_a[0][hy][hx] = a0;   lds_a[1][hy][hx] = a1;   lds_a[2][hy][hx] = a2;
    }
    __syncthreads();

    float local = 0.f, lepe = 0.f;
    const float T0 = 1.f / 12.f, T1 = 2.f / 3.f;
#pragma unroll
    for (int i = 0; i < 4; ++i) {
        int p = i * 256 + tid;
        int ly = p >> 5, lx = p & 31;
        int y = ty0 + ly, x = tx0 + lx;
        size_t fi = fbase + (size_t)y * WW + x;
        float fx = flowa[fi], fy = flowa[fi + PLANE];
        float X = (float)x + fx, Y = (float)y + fy;
        float mask = sigm(X + 0.5f) * (1.f - sigm(X - ((float)WW - 0.5f)))
                   * sigm(Y + 0.5f) * (1.f - sigm(Y - ((float)HH - 0.5f)));
        float wf[2];
        bilinN<2>(flowb + fbase, X, Y, wf);
        float mag = fx * fx + fy * fy + wf[0] * wf[0] + wf[1] * wf[1];
        float sx = fx + wf[0], sy = fy + wf[1];
        float d2 = sx * sx + sy * sy;
        mask *= 1.f - sigm(d2 - (0.01f * mag + 0.5f));
        float A = 0.f;
#pragma unroll
        for (int c = 0; c < 3; ++c) {
            float d = lds_a[c][ly + 2][lx + 2] - lds_w[c][ly + 2][lx + 2];
            A += d * d;
        }
        float sm = 0.f;
        if (x < WW - 1) {
            float dfx = flowa[fi + 1] - fx, dfy = flowa[fi + PLANE + 1] - fy;
            sm += dfx * dfx + dfy * dfy;
        }
        if (y < HH - 1) {
            float dfx = flowa[fi + WW] - fx, dfy = flowa[fi + PLANE + WW] - fy;
            sm += dfx * dfx + dfy * dfy;
        }
        float C = 0.f;
#pragma unroll
        for (int c = 0; c < 3; ++c) {
            float gha = T1 * (lds_a[c][ly + 2][lx + 1] - lds_a[c][ly + 2][lx + 3])
                      + T0 * (lds_a[c][ly + 2][lx + 4] - lds_a[c][ly + 2][lx]);
            float ghw = T1 * (lds_w[c][ly + 2][lx + 1] - lds_w[c][ly + 2][lx + 3])
                      + T0 * (lds_w[c][ly + 2][lx + 4] - lds_w[c][ly + 2][lx]);
            float d = gha - ghw; C += d * d;
            float gva = T1 * (lds_a[c][ly + 1][lx + 2] - lds_a[c][ly + 3][lx + 2])
                      + T0 * (lds_a[c][ly + 4][lx + 2] - lds_a[c][ly][lx + 2]);
            float gvw = T1 * (lds_w[c][ly + 1][lx + 2] - lds_w[c][ly + 3][lx + 2])
                      + T0 * (lds_w[c][ly + 4][lx + 2] - lds_w[c][ly][lx + 2]);
            d = gva - gvw; C += d * d;
        }
        local += sqrtf(A + 1e-5f) * mask + sqrtf(sm + 1e-5f)
               + sqrtf(C + 1e-5f) * mask + 12.4f * (1.f - mask)
               + sqrtf(d2 + 1e-5f) * mask;
        if (EPE) {
            float dx1 = fx - target[fi], dy1 = fy - target[fi + PLANE];
            lepe += sqrtf(dx1 * dx1 + dy1 * dy1);
        }
    }
    block_reduce_2(local, lepe, red, acc, EPE ? 1 : 0);
}

__global__ void finalize_kernel(const float* __restrict__ acc, float* __restrict__ out) {
    out[0] = acc[0] / (float)BB;
    out[1] = acc[1] / (float)((size_t)BB * HH * WW);
}

extern "C" void kernel_launch(void* const* d_in, const int* in_sizes, int n_in,
                              void* d_out, int out_size, void* d_ws, size_t ws_size,
                              hipStream_t stream) {
    const float* flowf  = (const float*)d_in[0];
    const float* flowb  = (const float*)d_in[1];
    const float* img1   = (const float*)d_in[2];
    const float* img2   = (const float*)d_in[3];
    const float* target = (const float*)d_in[4];
    float* out = (float*)d_out;
    float* acc = (float*)d_ws;

    hipMemsetAsync(acc, 0, 16, stream);

    const size_t need = 16 + (size_t)BB * PLANE * sizeof(float4);   // ~67 MB
    if (ws_size >= need) {
        float4* ebuf = (float4*)((char*)d_ws + 16);
        dim3 g1(WW / TILE, HH / TILE, BB);
        dim3 g2(WW / TILE, HH / TILE, BB);
        pass1_kernel<<<g1, 256, 0, stream>>>(flowf, flowb, img1, img2, target, ebuf, acc, 1);
        pass2_kernel<<<g2, 256, 0, stream>>>(ebuf, acc);
        pass1_kernel<<<g1, 256, 0, stream>>>(flowb, flowf, img2, img1, nullptr, ebuf, acc, 0);
        pass2_kernel<<<g2, 256, 0, stream>>>(ebuf, acc);
    } else {
        dim3 grid(WW / TILE, HH / TILE, BB);
        dir_kernel_fb<true ><<<grid, 256, 0, stream>>>(flowf, flowb, img1, img2, target, acc);
        dir_kernel_fb<false><<<grid, 256, 0, stream>>>(flowb, flowf, img2, img1, nullptr, acc);
    }

    finalize_kernel<<<1, 1, 0, stream>>>(acc, out);
}